// Round 17
// baseline (191.516 us; speedup 1.0000x reference)
//
#include <hip/hip_runtime.h>
#include <stdint.h>

#define NPIX 4096
#define CDIM 512

typedef _Float16 hv8 __attribute__((ext_vector_type(8)));
typedef float f32x4 __attribute__((ext_vector_type(4)));

__device__ __forceinline__ void lds_direct16(const _Float16* g, _Float16* l) {
    __builtin_amdgcn_global_load_lds(
        (const __attribute__((address_space(1))) void*)g,
        (__attribute__((address_space(3))) void*)l, 16, 0, 0);
}

// ---------------- groupnorm partial stats + weight fp32->fp16 conversion ----------------
__global__ void pstats_kernel(const float* __restrict__ x,
                              float* __restrict__ partS, float* __restrict__ partQ,
                              const float* __restrict__ wq, const float* __restrict__ wk,
                              const float* __restrict__ wv, const float* __restrict__ wo,
                              _Float16* __restrict__ d0, _Float16* __restrict__ d1,
                              _Float16* __restrict__ d2, _Float16* __restrict__ d3,
                              const float* __restrict__ bq, const float* __restrict__ bk,
                              float* __restrict__ bqk) {
    int pb = blockIdx.x;                 // 0..511
    int tid = threadIdx.x;

#pragma unroll
    for (int h = 0; h < 2; ++h) {
        int ii = pb * 512 + h * 256 + tid;
        d0[ii] = (_Float16)wq[ii];
        d1[ii] = (_Float16)wk[ii];
        d2[ii] = (_Float16)wv[ii];
        d3[ii] = (_Float16)wo[ii];
        if (ii < 512) bqk[ii] = bq[ii];
        else if (ii < 1024) bqk[ii] = bk[ii - 512];
    }

    int gi = pb >> 3;                    // global group 0..63
    int sl = pb & 7;                     // slice
    const float4* base = (const float4*)x + (long)gi * 16384 + sl * 2048;
    float s = 0.f, sq = 0.f;
    for (int it = 0; it < 8; ++it) {
        float4 f = base[it * 256 + tid];
        s  += f.x + f.y + f.z + f.w;
        sq += f.x * f.x + f.y * f.y + f.z * f.z + f.w * f.w;
    }
    __shared__ float rs[256], rq[256];
    rs[tid] = s; rq[tid] = sq;
    __syncthreads();
    for (int st = 128; st > 0; st >>= 1) {
        if (tid < st) { rs[tid] += rs[tid + st]; rq[tid] += rq[tid + st]; }
        __syncthreads();
    }
    if (tid == 0) { partS[pb] = rs[0]; partQ[pb] = rq[0]; }
}

// ---------------- normalize + transpose (stats finalized inline) ----------------
__global__ void normT_kernel(const float* __restrict__ x,
                             const float* __restrict__ partS, const float* __restrict__ partQ,
                             const float* __restrict__ gamma, const float* __restrict__ beta,
                             _Float16* __restrict__ hT) {
    int b = blockIdx.z, c0 = blockIdx.x * 32, n0 = blockIdx.y * 32;
    int tid = threadIdx.x;
    __shared__ float t[32][33];
    int cl = tid >> 5;
    int nl = tid & 31;
    for (int r = 0; r < 4; ++r)
        t[r * 8 + cl][nl] = x[(long)b * CDIM * NPIX + (long)(c0 + r * 8 + cl) * NPIX + n0 + nl];
    __syncthreads();
    int c = c0 + nl;
    int gg = b * 32 + (c >> 4);
    float s = 0.f, q = 0.f;
#pragma unroll
    for (int k2 = 0; k2 < 8; ++k2) { s += partS[gg * 8 + k2]; q += partQ[gg * 8 + k2]; }
    float m    = s * (1.0f / 65536.0f);
    float rstd = rsqrtf(q * (1.0f / 65536.0f) - m * m + 1e-6f);
    float gm = gamma[c], bt = beta[c];
    for (int r = 0; r < 4; ++r) {
        int nr = r * 8 + cl;
        float val = (t[nl][nr] - m) * rstd * gm + bt;
        hT[(long)b * NPIX * CDIM + (long)(n0 + nr) * CDIM + c] = (_Float16)val;
    }
}

// ---------------- bt-form GEMM: D[M][N] = A[M][K] * BT[N][K]^T ----------------
// EPI 1: fp16 store, bias[row]
// EPI 3: fused q|k -> col<512 to D (qT), col>=512 to D + 2*NPIX*CDIM (kT)
template<int EPI>
__launch_bounds__(256, 2)
__global__ void gemm_bt_kernel(const _Float16* __restrict__ A, const _Float16* __restrict__ BT,
                               void* __restrict__ D, const float* __restrict__ bias,
                               int M, int N, int K,
                               long aBatch, long bBatch, long dBatch) {
    const int b = blockIdx.z;
    A  += (long)b * aBatch;
    BT += (long)b * bBatch;
    const int m0 = blockIdx.y * 128;
    const int n0 = blockIdx.x * 128;
    const int tid = threadIdx.x;
    const int l = tid & 63;
    const int w = tid >> 6;
    const int wm = (w >> 1) * 64;
    const int wn = (w & 1) * 64;
    const int lr = l & 15;
    const int lk = l >> 4;
    __shared__ __align__(16) _Float16 As[128 * 32];
    __shared__ __align__(16) _Float16 Bs[128 * 32];
    f32x4 acc[4][4] = {};
    const int nK = K >> 5;
    for (int kt = 0; kt < nK; ++kt) {
        const int kb = kt * 32;
#pragma unroll
        for (int c = 0; c < 2; ++c) {
            int chunk = c * 256 + tid;
            int row = chunk >> 2;
            int k8 = (chunk & 3) * 8;
            _Float16* ldsA = As + (size_t)(c * 256 + (tid & ~63)) * 8;
            _Float16* ldsB = Bs + (size_t)(c * 256 + (tid & ~63)) * 8;
            lds_direct16(A  + (long)(m0 + row) * K + kb + k8, ldsA);
            lds_direct16(BT + (long)(n0 + row) * K + kb + k8, ldsB);
        }
        __syncthreads();
        hv8 af[4], bfr[4];
#pragma unroll
        for (int mi = 0; mi < 4; ++mi)
            af[mi] = *(const hv8*)(As + (size_t)(wm + mi * 16 + lr) * 32 + lk * 8);
#pragma unroll
        for (int ni = 0; ni < 4; ++ni)
            bfr[ni] = *(const hv8*)(Bs + (size_t)(wn + ni * 16 + lr) * 32 + lk * 8);
#pragma unroll
        for (int mi = 0; mi < 4; ++mi)
#pragma unroll
            for (int ni = 0; ni < 4; ++ni)
                acc[mi][ni] = __builtin_amdgcn_mfma_f32_16x16x32_f16(af[mi], bfr[ni], acc[mi][ni], 0, 0, 0);
        __syncthreads();
    }
#pragma unroll
    for (int mi = 0; mi < 4; ++mi)
#pragma unroll
        for (int ni = 0; ni < 4; ++ni)
#pragma unroll
            for (int r = 0; r < 4; ++r) {
                int row = m0 + wm + mi * 16 + lk * 4 + r;
                int col = n0 + wn + ni * 16 + lr;
                float val = acc[mi][ni][r];
                if (EPI == 1) {
                    ((_Float16*)D)[(long)b * dBatch + (long)row * N + col] = (_Float16)(val + bias[row]);
                } else {
                    long qoff = (long)(col >> 9) * (2L * NPIX * CDIM);
                    ((_Float16*)D)[qoff + (long)b * dBatch + (long)row * CDIM + (col & 511)] =
                        (_Float16)(val + bias[col]);
                }
            }
}

// ---------------- final GEMM with fused 4-way combine ----------------
__launch_bounds__(256, 2)
__global__ void gemm_final_kernel(const _Float16* __restrict__ A,      // wob [512][512]
                                  const _Float16* __restrict__ p0,
                                  const _Float16* __restrict__ p1,
                                  const _Float16* __restrict__ p2,
                                  const _Float16* __restrict__ p3,
                                  const float* __restrict__ lbuf,
                                  float* __restrict__ D, const float* __restrict__ bias,
                                  const float* __restrict__ resid) {
    const int b = blockIdx.z;
    const int m0 = blockIdx.y * 128;
    const int n0 = blockIdx.x * 128;
    const int tid = threadIdx.x;
    const int l = tid & 63;
    const int w = tid >> 6;
    const int wm = (w >> 1) * 64;
    const int wn = (w & 1) * 64;
    const int lr = l & 15;
    const int lk = l >> 4;
    __shared__ __align__(16) _Float16 As[128 * 32];
    __shared__ __align__(16) _Float16 Bs[128 * 32];
    __shared__ float wt[4][128];

    if (tid < 128) {
        int rowg = b * NPIX + n0 + tid;
        float l0 = lbuf[rowg], l1 = lbuf[8192 + rowg];
        float l2 = lbuf[16384 + rowg], l3 = lbuf[24576 + rowg];
        float inv = 1.0f / (l0 + l1 + l2 + l3);
        wt[0][tid] = l0 * inv; wt[1][tid] = l1 * inv;
        wt[2][tid] = l2 * inv; wt[3][tid] = l3 * inv;
    }
    __syncthreads();

    const _Float16* pb0 = p0 + (long)b * NPIX * CDIM;
    const _Float16* pb1 = p1 + (long)b * NPIX * CDIM;
    const _Float16* pb2 = p2 + (long)b * NPIX * CDIM;
    const _Float16* pb3 = p3 + (long)b * NPIX * CDIM;

    f32x4 acc[4][4] = {};
    for (int kt = 0; kt < 16; ++kt) {
        const int kb = kt * 32;
#pragma unroll
        for (int c = 0; c < 2; ++c) {
            int chunk = c * 256 + tid;
            int row = chunk >> 2;
            int k8 = (chunk & 3) * 8;
            _Float16* ldsA = As + (size_t)(c * 256 + (tid & ~63)) * 8;
            lds_direct16(A + (long)(m0 + row) * CDIM + kb + k8, ldsA);
            long goff = (long)(n0 + row) * CDIM + kb + k8;
            hv8 va = *(const hv8*)(pb0 + goff);
            hv8 vb = *(const hv8*)(pb1 + goff);
            hv8 vc = *(const hv8*)(pb2 + goff);
            hv8 vd = *(const hv8*)(pb3 + goff);
            float w0 = wt[0][row], w1 = wt[1][row], w2 = wt[2][row], w3 = wt[3][row];
            hv8 vo;
#pragma unroll
            for (int i = 0; i < 8; ++i)
                vo[i] = (_Float16)((float)va[i] * w0 + (float)vb[i] * w1
                                 + (float)vc[i] * w2 + (float)vd[i] * w3);
            *(hv8*)(Bs + (size_t)chunk * 8) = vo;
        }
        __syncthreads();
        hv8 af[4], bfr[4];
#pragma unroll
        for (int mi = 0; mi < 4; ++mi)
            af[mi] = *(const hv8*)(As + (size_t)(wm + mi * 16 + lr) * 32 + lk * 8);
#pragma unroll
        for (int ni = 0; ni < 4; ++ni)
            bfr[ni] = *(const hv8*)(Bs + (size_t)(wn + ni * 16 + lr) * 32 + lk * 8);
#pragma unroll
        for (int mi = 0; mi < 4; ++mi)
#pragma unroll
            for (int ni = 0; ni < 4; ++ni)
                acc[mi][ni] = __builtin_amdgcn_mfma_f32_16x16x32_f16(af[mi], bfr[ni], acc[mi][ni], 0, 0, 0);
        __syncthreads();
    }
#pragma unroll
    for (int mi = 0; mi < 4; ++mi)
#pragma unroll
        for (int ni = 0; ni < 4; ++ni)
#pragma unroll
            for (int r = 0; r < 4; ++r) {
                int row = m0 + wm + mi * 16 + lk * 4 + r;
                int col = n0 + wn + ni * 16 + lr;
                long idx = (long)row * NPIX + col;
                D[(long)b * NPIX * CDIM + idx] =
                    acc[mi][ni][r] + bias[row] + resid[(long)b * NPIX * CDIM + idx];
            }
}

// ---------------- flash attention v17: v11 structure, j-split 4, 2 blocks/CU ----------------
// Identical per-wave structure/registers to v11 (116 VGPR, no spill). Grid 512:
// each (batch, j-quarter) pins to ONE XCD (K+V quarter = 2 MB L2-resident);
// LDS 76.8 KB x 2 = 153.6 <= 160 -> hardware co-schedules 2 blocks/CU, hiding
// each other's end-of-step barrier drains. 32 steps of 32 j.
__launch_bounds__(512, 2)
__global__ void attn_kernel(const _Float16* __restrict__ qT, const _Float16* __restrict__ kT,
                            const _Float16* __restrict__ v,
                            _Float16* __restrict__ p0, _Float16* __restrict__ p1,
                            _Float16* __restrict__ p2, _Float16* __restrict__ p3,
                            float* __restrict__ lbuf) {
    __shared__ __align__(16) _Float16 Ks[2][32 * 512];   // 64 KB, rows 1 KB, XOR (j&7)<<4
    __shared__ __align__(16) char ps[2][64 * 80];        // 10 KB, 80 B rows
    __shared__ float red[8][64];
    __shared__ float redt[64];

    const int g = blockIdx.x;                        // 0..511
    const int xcd = g & 7;
    const int batch = xcd >> 2;
    const int jq4 = xcd & 3;
    const int itile = g >> 3;                        // 0..63
    const int i0 = itile * 64;
    const int jbase = jq4 * 1024;

    const int tid = threadIdx.x;
    const int l = tid & 63, w = tid >> 6;
    const int lr = l & 15, lk = l >> 4;
    const int iq = w >> 1, jq = w & 1;               // QK: rows iq*16, cols jq*16

    const _Float16* qb = qT + (long)batch * NPIX * CDIM;
    const _Float16* kb = kT + (long)batch * NPIX * CDIM;
    const _Float16* vb = v  + (long)batch * CDIM * NPIX;

    hv8 af[16];
    {
        const _Float16* qr = qb + (long)(i0 + iq * 16 + lr) * CDIM + lk * 8;
#pragma unroll
        for (int kk = 0; kk < 16; ++kk)
            af[kk] = *(const hv8*)(qr + kk * 32);
    }

    f32x4 oacc[4][4] = {};
    float lsum[4] = {};
    hv8 vf[4];

    const _Float16* vptr = vb + (long)(w * 64 + lr) * NPIX + jbase + lk * 8;
    const float scale = 0.044194173824159216f;   // 1/sqrt(512)

#define STAGE(BUF, JT)                                                               \
    {                                                                                \
        const long j0s = (long)jbase + (JT) * 32;                                    \
        _Float16* kd = Ks[BUF];                                                      \
        _Pragma("unroll")                                                            \
        for (int q = 0; q < 4; ++q) {                                                \
            int row = q * 8 + w;                                                     \
            int cc = l ^ (row & 7);                                                  \
            lds_direct16(kb + (j0s + row) * CDIM + cc * 8, kd + row * 512);          \
        }                                                                            \
    }

#define VLOAD(JT)                                                                    \
    {                                                                                \
        _Pragma("unroll")                                                            \
        for (int ni = 0; ni < 4; ++ni)                                               \
            vf[ni] = *(const hv8*)(vptr + (long)ni * (16 * NPIX) + (JT) * 32);       \
    }

#define QKEXP(CUR)                                                                   \
    {                                                                                \
        const char* kbase = (const char*)Ks[CUR];                                    \
        f32x4 sa = {}, sb = {};                                                      \
        const int jj = jq * 16 + lr;                                                 \
        const uint32_t sw = (uint32_t)((jj & 7) << 4);                               \
        _Pragma("unroll")                                                            \
        for (int kk = 0; kk < 8; ++kk) {                                             \
            hv8 b0 = *(const hv8*)(kbase + (((uint32_t)(jj * 1024 + (2 * kk) * 64 + lk * 16)) ^ sw));     \
            sa = __builtin_amdgcn_mfma_f32_16x16x32_f16(af[2 * kk], b0, sa, 0, 0, 0);                     \
            hv8 b1 = *(const hv8*)(kbase + (((uint32_t)(jj * 1024 + (2 * kk + 1) * 64 + lk * 16)) ^ sw)); \
            sb = __builtin_amdgcn_mfma_f32_16x16x32_f16(af[2 * kk + 1], b1, sb, 0, 0, 0);                 \
        }                                                                            \
        sa += sb;                                                                    \
        _Pragma("unroll")                                                            \
        for (int r = 0; r < 4; ++r) {                                                \
            float p = __expf(sa[r] * scale);                                         \
            lsum[r] += p;                                                            \
            int i = iq * 16 + lk * 4 + r;                                            \
            int j2 = jq * 16 + lr;                                                   \
            *(_Float16*)(ps[CUR] + i * 80 + j2 * 2) = (_Float16)p;                   \
        }                                                                            \
    }

#define PVSTEP(PRV)                                                                  \
    {                                                                                \
        _Pragma("unroll")                                                            \
        for (int mi = 0; mi < 4; ++mi) {                                             \
            int i2 = mi * 16 + lr;                                                   \
            hv8 pa = *(const hv8*)(ps[PRV] + i2 * 80 + lk * 16);                     \
            _Pragma("unroll")                                                        \
            for (int ni = 0; ni < 4; ++ni)                                           \
                oacc[mi][ni] = __builtin_amdgcn_mfma_f32_16x16x32_f16(pa, vf[ni], oacc[mi][ni], 0, 0, 0); \
        }                                                                            \
    }

#define ENDBAR(N)                                                                    \
    __builtin_amdgcn_sched_barrier(0);                                               \
    asm volatile("s_waitcnt vmcnt(" #N ") lgkmcnt(0)" ::: "memory");                 \
    __builtin_amdgcn_s_barrier();                                                    \
    __builtin_amdgcn_sched_barrier(0);

#define STEP(JT, CUR)                                                                \
    {                                                                                \
        if ((JT) < 31) STAGE((CUR) ^ 1, (JT) + 1)                                    \
        __builtin_amdgcn_sched_barrier(0);                                           \
        __builtin_amdgcn_s_setprio(1);                                               \
        QKEXP(CUR)                                                                   \
        PVSTEP((CUR) ^ 1)                                                            \
        __builtin_amdgcn_s_setprio(0);                                               \
        __builtin_amdgcn_sched_barrier(0);                                           \
        VLOAD(JT)                                                                    \
        ENDBAR(4)                                                                    \
    }

    STAGE(0, 0)
    __builtin_amdgcn_sched_barrier(0);
    asm volatile("s_waitcnt vmcnt(0)" ::: "memory");
    __builtin_amdgcn_s_barrier();
    __builtin_amdgcn_sched_barrier(0);

    STAGE(1, 1)
    __builtin_amdgcn_s_setprio(1);
    QKEXP(0)
    __builtin_amdgcn_s_setprio(0);
    VLOAD(0)
    ENDBAR(4)

    for (int jt = 1; jt < 31; jt += 2) {
        STEP(jt,     1)
        STEP(jt + 1, 0)
    }
    STEP(31, 1)

    asm volatile("s_waitcnt vmcnt(0)" ::: "memory");
    __builtin_amdgcn_sched_barrier(0);
    PVSTEP(1)

#pragma unroll
    for (int m = 1; m <= 8; m <<= 1)
#pragma unroll
        for (int r = 0; r < 4; ++r)
            lsum[r] += __shfl_xor(lsum[r], m, 64);
    if (lr == 0)
#pragma unroll
        for (int r = 0; r < 4; ++r)
            red[w][iq * 16 + lk * 4 + r] = lsum[r];
    __syncthreads();
    if (tid < 64) {
        int iq2 = tid >> 4;
        float lv = red[iq2 * 2][tid] + red[iq2 * 2 + 1][tid];
        redt[tid] = 1.0f / lv;
        lbuf[jq4 * 8192 + batch * NPIX + i0 + tid] = lv;
    }
    __syncthreads();

    _Float16* dsth = (jq4 == 0 ? p0 : jq4 == 1 ? p1 : jq4 == 2 ? p2 : p3)
                   + (long)batch * NPIX * CDIM;
#pragma unroll
    for (int mi = 0; mi < 4; ++mi)
#pragma unroll
        for (int r = 0; r < 4; ++r) {
            int row = mi * 16 + lk * 4 + r;
            float rv = redt[row];
#pragma unroll
            for (int ni = 0; ni < 4; ++ni) {
                int c = w * 64 + ni * 16 + lr;
                dsth[(long)(i0 + row) * CDIM + c] = (_Float16)(oacc[mi][ni][r] * rv);
            }
        }
#undef STEP
#undef ENDBAR
#undef PVSTEP
#undef QKEXP
#undef VLOAD
#undef STAGE
}

extern "C" void kernel_launch(void* const* d_in, const int* in_sizes, int n_in,
                              void* d_out, int out_size, void* d_ws, size_t ws_size,
                              hipStream_t stream) {
    const float* x     = (const float*)d_in[0];
    const float* gamma = (const float*)d_in[1];
    const float* beta  = (const float*)d_in[2];
    const float* wq    = (const float*)d_in[3];
    const float* bq    = (const float*)d_in[4];
    const float* wk    = (const float*)d_in[5];
    const float* bk    = (const float*)d_in[6];
    const float* wv    = (const float*)d_in[7];
    const float* bv    = (const float*)d_in[8];
    const float* wo    = (const float*)d_in[9];
    const float* bo    = (const float*)d_in[10];
    float* out = (float*)d_out;

    char* ws = (char*)d_ws;
    float* partS = (float*)ws;               // 512
    float* partQ = partS + 512;              // 512
    float* bqk   = partQ + 512;              // 1024
    _Float16* wqb = (_Float16*)(ws + 8192);  // wq|wk adjacent -> fused BT [1024][512]
    _Float16* wkb = wqb + 262144;
    _Float16* wvb = wkb + 262144;
    _Float16* wob = wvb + 262144;
    _Float16* hT  = wob + 262144;
    const long TSZ = (long)2 * NPIX * CDIM;
    _Float16* qT = hT + TSZ;
    _Float16* kT = qT + TSZ;                 // = qT + 2*NPIX*CDIM (EPI3 relies on this)
    _Float16* vv = kT + TSZ;
    _Float16* oT = vv + TSZ;
    float* lbuf = (float*)(oT + TSZ);        // 4 quarters x 8192 rows (128 KB)
    _Float16* pq2 = (_Float16*)(lbuf + 32768);
    _Float16* pq3 = pq2 + TSZ;

    pstats_kernel<<<dim3(512), dim3(256), 0, stream>>>(
        x, partS, partQ, wq, wk, wv, wo, wqb, wkb, wvb, wob, bq, bk, bqk);
    normT_kernel<<<dim3(16, 128, 2), dim3(256), 0, stream>>>(x, partS, partQ, gamma, beta, hT);

    const long NC = (long)NPIX * CDIM;
    gemm_bt_kernel<3><<<dim3(8, 32, 2), dim3(256), 0, stream>>>(
        hT, wqb, (void*)qT, bqk, NPIX, 1024, CDIM, NC, 0L, NC);
    gemm_bt_kernel<1><<<dim3(32, 4, 2), dim3(256), 0, stream>>>(
        wvb, hT, (void*)vv, bv, CDIM, NPIX, CDIM, 0L, NC, NC);

    // attention: quarters -> oT, hT (dead), pq2, pq3; sums -> lbuf
    attn_kernel<<<dim3(512), dim3(512), 0, stream>>>(qT, kT, vv, oT, hT, pq2, pq3, lbuf);

    // final GEMM with fused 4-way combine: out = wo *bt (sum wq*Oq) + bo + x
    gemm_final_kernel<<<dim3(32, 4, 2), dim3(256), 0, stream>>>(
        wob, oT, hT, pq2, pq3, lbuf, out, bo, x);
}

// Round 18
// 170.784 us; speedup vs baseline: 1.1214x; 1.1214x over previous
//
#include <hip/hip_runtime.h>
#include <stdint.h>

#define NPIX 4096
#define CDIM 512

typedef _Float16 hv8 __attribute__((ext_vector_type(8)));
typedef float f32x4 __attribute__((ext_vector_type(4)));

__device__ __forceinline__ void lds_direct16(const _Float16* g, _Float16* l) {
    __builtin_amdgcn_global_load_lds(
        (const __attribute__((address_space(1))) void*)g,
        (__attribute__((address_space(3))) void*)l, 16, 0, 0);
}

// ---------------- groupnorm partial stats + weight fp32->fp16 conversion ----------------
__global__ void pstats_kernel(const float* __restrict__ x,
                              float* __restrict__ partS, float* __restrict__ partQ,
                              const float* __restrict__ wq, const float* __restrict__ wk,
                              const float* __restrict__ wv, const float* __restrict__ wo,
                              _Float16* __restrict__ d0, _Float16* __restrict__ d1,
                              _Float16* __restrict__ d2, _Float16* __restrict__ d3,
                              const float* __restrict__ bq, const float* __restrict__ bk,
                              float* __restrict__ bqk) {
    int pb = blockIdx.x;                 // 0..511
    int tid = threadIdx.x;

#pragma unroll
    for (int h = 0; h < 2; ++h) {
        int ii = pb * 512 + h * 256 + tid;
        d0[ii] = (_Float16)wq[ii];
        d1[ii] = (_Float16)wk[ii];
        d2[ii] = (_Float16)wv[ii];
        d3[ii] = (_Float16)wo[ii];
        if (ii < 512) bqk[ii] = bq[ii];
        else if (ii < 1024) bqk[ii] = bk[ii - 512];
    }

    int gi = pb >> 3;                    // global group 0..63
    int sl = pb & 7;                     // slice
    const float4* base = (const float4*)x + (long)gi * 16384 + sl * 2048;
    float s = 0.f, sq = 0.f;
    for (int it = 0; it < 8; ++it) {
        float4 f = base[it * 256 + tid];
        s  += f.x + f.y + f.z + f.w;
        sq += f.x * f.x + f.y * f.y + f.z * f.z + f.w * f.w;
    }
    __shared__ float rs[256], rq[256];
    rs[tid] = s; rq[tid] = sq;
    __syncthreads();
    for (int st = 128; st > 0; st >>= 1) {
        if (tid < st) { rs[tid] += rs[tid + st]; rq[tid] += rq[tid + st]; }
        __syncthreads();
    }
    if (tid == 0) { partS[pb] = rs[0]; partQ[pb] = rq[0]; }
}

// ---------------- normalize + transpose (stats finalized inline) ----------------
__global__ void normT_kernel(const float* __restrict__ x,
                             const float* __restrict__ partS, const float* __restrict__ partQ,
                             const float* __restrict__ gamma, const float* __restrict__ beta,
                             _Float16* __restrict__ hT) {
    int b = blockIdx.z, c0 = blockIdx.x * 32, n0 = blockIdx.y * 32;
    int tid = threadIdx.x;
    __shared__ float t[32][33];
    int cl = tid >> 5;
    int nl = tid & 31;
    for (int r = 0; r < 4; ++r)
        t[r * 8 + cl][nl] = x[(long)b * CDIM * NPIX + (long)(c0 + r * 8 + cl) * NPIX + n0 + nl];
    __syncthreads();
    int c = c0 + nl;
    int gg = b * 32 + (c >> 4);
    float s = 0.f, q = 0.f;
#pragma unroll
    for (int k2 = 0; k2 < 8; ++k2) { s += partS[gg * 8 + k2]; q += partQ[gg * 8 + k2]; }
    float m    = s * (1.0f / 65536.0f);
    float rstd = rsqrtf(q * (1.0f / 65536.0f) - m * m + 1e-6f);
    float gm = gamma[c], bt = beta[c];
    for (int r = 0; r < 4; ++r) {
        int nr = r * 8 + cl;
        float val = (t[nl][nr] - m) * rstd * gm + bt;
        hT[(long)b * NPIX * CDIM + (long)(n0 + nr) * CDIM + c] = (_Float16)val;
    }
}

// ---------------- merged q|k + v GEMM, single launch ----------------
// blockIdx.x < 256: q|k GEMM  D[4096][1024] = hT * [wq|wk]^T, split-store to qT/kT.
// blockIdx.x >= 256: v GEMM   vv[512][4096] = wv * hT^T (bt), bias[row].
__device__ __forceinline__ void gemm_body(
    const _Float16* A, const _Float16* BT, int m0, int n0, int K,
    _Float16* As, _Float16* Bs, f32x4 (&acc)[4][4],
    int tid, int wm, int wn, int lr, int lk) {
    const int nK = K >> 5;
    for (int kt = 0; kt < nK; ++kt) {
        const int kb = kt * 32;
#pragma unroll
        for (int c = 0; c < 2; ++c) {
            int chunk = c * 256 + tid;
            int row = chunk >> 2;
            int k8 = (chunk & 3) * 8;
            _Float16* ldsA = As + (size_t)(c * 256 + (tid & ~63)) * 8;
            _Float16* ldsB = Bs + (size_t)(c * 256 + (tid & ~63)) * 8;
            lds_direct16(A  + (long)(m0 + row) * K + kb + k8, ldsA);
            lds_direct16(BT + (long)(n0 + row) * K + kb + k8, ldsB);
        }
        __syncthreads();
        hv8 af[4], bfr[4];
#pragma unroll
        for (int mi = 0; mi < 4; ++mi)
            af[mi] = *(const hv8*)(As + (size_t)(wm + mi * 16 + lr) * 32 + lk * 8);
#pragma unroll
        for (int ni = 0; ni < 4; ++ni)
            bfr[ni] = *(const hv8*)(Bs + (size_t)(wn + ni * 16 + lr) * 32 + lk * 8);
#pragma unroll
        for (int mi = 0; mi < 4; ++mi)
#pragma unroll
            for (int ni = 0; ni < 4; ++ni)
                acc[mi][ni] = __builtin_amdgcn_mfma_f32_16x16x32_f16(af[mi], bfr[ni], acc[mi][ni], 0, 0, 0);
        __syncthreads();
    }
}

__launch_bounds__(256, 2)
__global__ void gemm_qkv_kernel(const _Float16* __restrict__ hT, const _Float16* __restrict__ wqk,
                                const _Float16* __restrict__ wvb,
                                _Float16* __restrict__ qT, _Float16* __restrict__ vv,
                                const float* __restrict__ bqk, const float* __restrict__ bv) {
    const int b = blockIdx.z;
    const long NC = (long)NPIX * CDIM;
    const int tid = threadIdx.x;
    const int l = tid & 63;
    const int w = tid >> 6;
    const int wm = (w >> 1) * 64;
    const int wn = (w & 1) * 64;
    const int lr = l & 15;
    const int lk = l >> 4;
    __shared__ __align__(16) _Float16 As[128 * 32];
    __shared__ __align__(16) _Float16 Bs[128 * 32];
    f32x4 acc[4][4] = {};

    if (blockIdx.x < 256) {
        // q|k: M=4096 (A=hT batch b), N=1024 (BT=wqk), tiles 8 x 32
        const int n0 = (blockIdx.x & 7) * 128;
        const int m0 = (blockIdx.x >> 3) * 128;
        gemm_body(hT + (long)b * NC, wqk, m0, n0, CDIM, As, Bs, acc, tid, wm, wn, lr, lk);
#pragma unroll
        for (int mi = 0; mi < 4; ++mi)
#pragma unroll
            for (int ni = 0; ni < 4; ++ni)
#pragma unroll
                for (int r = 0; r < 4; ++r) {
                    int row = m0 + wm + mi * 16 + lk * 4 + r;
                    int col = n0 + wn + ni * 16 + lr;
                    long qoff = (long)(col >> 9) * (2L * NC);
                    qT[qoff + (long)b * NC + (long)row * CDIM + (col & 511)] =
                        (_Float16)(acc[mi][ni][r] + bqk[col]);
                }
    } else {
        // v: M=512 (A=wvb), N=4096 (BT=hT batch b), tiles 32 x 4
        const int xx = blockIdx.x - 256;
        const int n0 = (xx & 31) * 128;
        const int m0 = (xx >> 5) * 128;
        gemm_body(wvb, hT + (long)b * NC, m0, n0, CDIM, As, Bs, acc, tid, wm, wn, lr, lk);
#pragma unroll
        for (int mi = 0; mi < 4; ++mi)
#pragma unroll
            for (int ni = 0; ni < 4; ++ni)
#pragma unroll
                for (int r = 0; r < 4; ++r) {
                    int row = m0 + wm + mi * 16 + lk * 4 + r;
                    int col = n0 + wn + ni * 16 + lr;
                    vv[(long)b * NC + (long)row * NPIX + col] =
                        (_Float16)(acc[mi][ni][r] + bv[row]);
                }
    }
}

// ---------------- final GEMM with fused combine ----------------
__launch_bounds__(256, 2)
__global__ void gemm_final_kernel(const _Float16* __restrict__ A,      // wob [512][512]
                                  const _Float16* __restrict__ p0,
                                  const _Float16* __restrict__ p1,
                                  const float* __restrict__ lbuf,
                                  float* __restrict__ D, const float* __restrict__ bias,
                                  const float* __restrict__ resid) {
    const int b = blockIdx.z;
    const int m0 = blockIdx.y * 128;
    const int n0 = blockIdx.x * 128;
    const int tid = threadIdx.x;
    const int l = tid & 63;
    const int w = tid >> 6;
    const int wm = (w >> 1) * 64;
    const int wn = (w & 1) * 64;
    const int lr = l & 15;
    const int lk = l >> 4;
    __shared__ __align__(16) _Float16 As[128 * 32];
    __shared__ __align__(16) _Float16 Bs[128 * 32];
    __shared__ float wA[128], wB[128];

    if (tid < 128) {
        int rowg = b * NPIX + n0 + tid;
        float l0 = lbuf[rowg], l1 = lbuf[8192 + rowg];
        float inv = 1.0f / (l0 + l1);
        wA[tid] = l0 * inv;
        wB[tid] = l1 * inv;
    }
    __syncthreads();

    const _Float16* pb0 = p0 + (long)b * NPIX * CDIM;
    const _Float16* pb1 = p1 + (long)b * NPIX * CDIM;

    f32x4 acc[4][4] = {};
    for (int kt = 0; kt < 16; ++kt) {
        const int kb = kt * 32;
#pragma unroll
        for (int c = 0; c < 2; ++c) {
            int chunk = c * 256 + tid;
            int row = chunk >> 2;
            int k8 = (chunk & 3) * 8;
            _Float16* ldsA = As + (size_t)(c * 256 + (tid & ~63)) * 8;
            lds_direct16(A + (long)(m0 + row) * CDIM + kb + k8, ldsA);
            long goff = (long)(n0 + row) * CDIM + kb + k8;
            hv8 va = *(const hv8*)(pb0 + goff);
            hv8 vb = *(const hv8*)(pb1 + goff);
            float w0 = wA[row], w1 = wB[row];
            hv8 vo;
#pragma unroll
            for (int i = 0; i < 8; ++i)
                vo[i] = (_Float16)((float)va[i] * w0 + (float)vb[i] * w1);
            *(hv8*)(Bs + (size_t)chunk * 8) = vo;
        }
        __syncthreads();
        hv8 af[4], bfr[4];
#pragma unroll
        for (int mi = 0; mi < 4; ++mi)
            af[mi] = *(const hv8*)(As + (size_t)(wm + mi * 16 + lr) * 32 + lk * 8);
#pragma unroll
        for (int ni = 0; ni < 4; ++ni)
            bfr[ni] = *(const hv8*)(Bs + (size_t)(wn + ni * 16 + lr) * 32 + lk * 8);
#pragma unroll
        for (int mi = 0; mi < 4; ++mi)
#pragma unroll
            for (int ni = 0; ni < 4; ++ni)
                acc[mi][ni] = __builtin_amdgcn_mfma_f32_16x16x32_f16(af[mi], bfr[ni], acc[mi][ni], 0, 0, 0);
        __syncthreads();
    }
#pragma unroll
    for (int mi = 0; mi < 4; ++mi)
#pragma unroll
        for (int ni = 0; ni < 4; ++ni)
#pragma unroll
            for (int r = 0; r < 4; ++r) {
                int row = m0 + wm + mi * 16 + lk * 4 + r;
                int col = n0 + wn + ni * 16 + lr;
                long idx = (long)row * NPIX + col;
                D[(long)b * NPIX * CDIM + idx] =
                    acc[mi][ni][r] + bias[row] + resid[(long)b * NPIX * CDIM + idx];
            }
}

// ---------------- flash attention v11 (champion, unchanged) ----------------
__launch_bounds__(512, 2)
__global__ void attn_kernel(const _Float16* __restrict__ qT, const _Float16* __restrict__ kT,
                            const _Float16* __restrict__ v,
                            _Float16* __restrict__ p0, _Float16* __restrict__ p1,
                            float* __restrict__ lbuf) {
    __shared__ __align__(16) _Float16 Ks[2][32 * 512];   // 64 KB, rows 1 KB, XOR (j&7)<<4
    __shared__ __align__(16) char ps[2][64 * 80];        // 10 KB, 80 B rows
    __shared__ float red[8][64];
    __shared__ float redt[64];

    const int g = blockIdx.x;
    const int xcd = g & 7;
    const int comb = xcd >> 1;                       // (batch, jhalf)
    const int itile = ((g >> 3) << 1) | (xcd & 1);   // 0..63
    const int batch = comb >> 1;
    const int jhalf = comb & 1;
    const int i0 = itile * 64;
    const int jbase = jhalf * 2048;

    const int tid = threadIdx.x;
    const int l = tid & 63, w = tid >> 6;
    const int lr = l & 15, lk = l >> 4;
    const int iq = w >> 1, jq = w & 1;               // QK: rows iq*16, cols jq*16

    const _Float16* qb = qT + (long)batch * NPIX * CDIM;
    const _Float16* kb = kT + (long)batch * NPIX * CDIM;
    const _Float16* vb = v  + (long)batch * CDIM * NPIX;

    hv8 af[16];
    {
        const _Float16* qr = qb + (long)(i0 + iq * 16 + lr) * CDIM + lk * 8;
#pragma unroll
        for (int kk = 0; kk < 16; ++kk)
            af[kk] = *(const hv8*)(qr + kk * 32);
    }

    f32x4 oacc[4][4] = {};
    float lsum[4] = {};
    hv8 vf[4];

    const _Float16* vptr = vb + (long)(w * 64 + lr) * NPIX + jbase + lk * 8;
    const float scale = 0.044194173824159216f;   // 1/sqrt(512)

#define STAGE(BUF, JT)                                                               \
    {                                                                                \
        const long j0s = (long)jbase + (JT) * 32;                                    \
        _Float16* kd = Ks[BUF];                                                      \
        _Pragma("unroll")                                                            \
        for (int q = 0; q < 4; ++q) {                                                \
            int row = q * 8 + w;                                                     \
            int cc = l ^ (row & 7);                                                  \
            lds_direct16(kb + (j0s + row) * CDIM + cc * 8, kd + row * 512);          \
        }                                                                            \
    }

#define VLOAD(JT)                                                                    \
    {                                                                                \
        _Pragma("unroll")                                                            \
        for (int ni = 0; ni < 4; ++ni)                                               \
            vf[ni] = *(const hv8*)(vptr + (long)ni * (16 * NPIX) + (JT) * 32);       \
    }

#define QKEXP(CUR)                                                                   \
    {                                                                                \
        const char* kbase = (const char*)Ks[CUR];                                    \
        f32x4 sa = {}, sb = {};                                                      \
        const int jj = jq * 16 + lr;                                                 \
        const uint32_t sw = (uint32_t)((jj & 7) << 4);                               \
        _Pragma("unroll")                                                            \
        for (int kk = 0; kk < 8; ++kk) {                                             \
            hv8 b0 = *(const hv8*)(kbase + (((uint32_t)(jj * 1024 + (2 * kk) * 64 + lk * 16)) ^ sw));     \
            sa = __builtin_amdgcn_mfma_f32_16x16x32_f16(af[2 * kk], b0, sa, 0, 0, 0);                     \
            hv8 b1 = *(const hv8*)(kbase + (((uint32_t)(jj * 1024 + (2 * kk + 1) * 64 + lk * 16)) ^ sw)); \
            sb = __builtin_amdgcn_mfma_f32_16x16x32_f16(af[2 * kk + 1], b1, sb, 0, 0, 0);                 \
        }                                                                            \
        sa += sb;                                                                    \
        _Pragma("unroll")                                                            \
        for (int r = 0; r < 4; ++r) {                                                \
            float p = __expf(sa[r] * scale);                                         \
            lsum[r] += p;                                                            \
            int i = iq * 16 + lk * 4 + r;                                            \
            int j2 = jq * 16 + lr;                                                   \
            *(_Float16*)(ps[CUR] + i * 80 + j2 * 2) = (_Float16)p;                   \
        }                                                                            \
    }

#define PVSTEP(PRV)                                                                  \
    {                                                                                \
        _Pragma("unroll")                                                            \
        for (int mi = 0; mi < 4; ++mi) {                                             \
            int i2 = mi * 16 + lr;                                                   \
            hv8 pa = *(const hv8*)(ps[PRV] + i2 * 80 + lk * 16);                     \
            _Pragma("unroll")                                                        \
            for (int ni = 0; ni < 4; ++ni)                                           \
                oacc[mi][ni] = __builtin_amdgcn_mfma_f32_16x16x32_f16(pa, vf[ni], oacc[mi][ni], 0, 0, 0); \
        }                                                                            \
    }

#define ENDBAR(N)                                                                    \
    __builtin_amdgcn_sched_barrier(0);                                               \
    asm volatile("s_waitcnt vmcnt(" #N ") lgkmcnt(0)" ::: "memory");                 \
    __builtin_amdgcn_s_barrier();                                                    \
    __builtin_amdgcn_sched_barrier(0);

#define STEP(JT, CUR)                                                                \
    {                                                                                \
        if ((JT) < 63) STAGE((CUR) ^ 1, (JT) + 1)                                    \
        __builtin_amdgcn_sched_barrier(0);                                           \
        __builtin_amdgcn_s_setprio(1);                                               \
        QKEXP(CUR)                                                                   \
        PVSTEP((CUR) ^ 1)                                                            \
        __builtin_amdgcn_s_setprio(0);                                               \
        __builtin_amdgcn_sched_barrier(0);                                           \
        VLOAD(JT)                                                                    \
        ENDBAR(4)                                                                    \
    }

    STAGE(0, 0)
    __builtin_amdgcn_sched_barrier(0);
    asm volatile("s_waitcnt vmcnt(0)" ::: "memory");
    __builtin_amdgcn_s_barrier();
    __builtin_amdgcn_sched_barrier(0);

    STAGE(1, 1)
    __builtin_amdgcn_s_setprio(1);
    QKEXP(0)
    __builtin_amdgcn_s_setprio(0);
    VLOAD(0)
    ENDBAR(4)

    for (int jt = 1; jt < 63; jt += 2) {
        STEP(jt,     1)
        STEP(jt + 1, 0)
    }
    STEP(63, 1)

    asm volatile("s_waitcnt vmcnt(0)" ::: "memory");
    __builtin_amdgcn_sched_barrier(0);
    PVSTEP(1)

#pragma unroll
    for (int m = 1; m <= 8; m <<= 1)
#pragma unroll
        for (int r = 0; r < 4; ++r)
            lsum[r] += __shfl_xor(lsum[r], m, 64);
    if (lr == 0)
#pragma unroll
        for (int r = 0; r < 4; ++r)
            red[w][iq * 16 + lk * 4 + r] = lsum[r];
    __syncthreads();
    if (tid < 64) {
        int iq2 = tid >> 4;
        float lv = red[iq2 * 2][tid] + red[iq2 * 2 + 1][tid];
        redt[tid] = 1.0f / lv;
        lbuf[jhalf * 8192 + batch * NPIX + i0 + tid] = lv;
    }
    __syncthreads();

    _Float16* dsth = (jhalf ? p1 : p0) + (long)batch * NPIX * CDIM;
#pragma unroll
    for (int mi = 0; mi < 4; ++mi)
#pragma unroll
        for (int r = 0; r < 4; ++r) {
            int row = mi * 16 + lk * 4 + r;
            float rv = redt[row];
#pragma unroll
            for (int ni = 0; ni < 4; ++ni) {
                int c = w * 64 + ni * 16 + lr;
                dsth[(long)(i0 + row) * CDIM + c] = (_Float16)(oacc[mi][ni][r] * rv);
            }
        }
#undef STEP
#undef ENDBAR
#undef PVSTEP
#undef QKEXP
#undef VLOAD
#undef STAGE
}

extern "C" void kernel_launch(void* const* d_in, const int* in_sizes, int n_in,
                              void* d_out, int out_size, void* d_ws, size_t ws_size,
                              hipStream_t stream) {
    const float* x     = (const float*)d_in[0];
    const float* gamma = (const float*)d_in[1];
    const float* beta  = (const float*)d_in[2];
    const float* wq    = (const float*)d_in[3];
    const float* bq    = (const float*)d_in[4];
    const float* wk    = (const float*)d_in[5];
    const float* bk    = (const float*)d_in[6];
    const float* wv    = (const float*)d_in[7];
    const float* bv    = (const float*)d_in[8];
    const float* wo    = (const float*)d_in[9];
    const float* bo    = (const float*)d_in[10];
    float* out = (float*)d_out;

    char* ws = (char*)d_ws;
    float* partS = (float*)ws;               // 512
    float* partQ = partS + 512;              // 512
    float* bqk   = partQ + 512;              // 1024
    _Float16* wqb = (_Float16*)(ws + 8192);  // wq|wk adjacent -> fused BT [1024][512]
    _Float16* wkb = wqb + 262144;
    _Float16* wvb = wkb + 262144;
    _Float16* wob = wvb + 262144;
    _Float16* hT  = wob + 262144;
    const long TSZ = (long)2 * NPIX * CDIM;
    _Float16* qT = hT + TSZ;
    _Float16* kT = qT + TSZ;                 // = qT + 2*NPIX*CDIM (split-store relies on this)
    _Float16* vv = kT + TSZ;
    _Float16* oT = vv + TSZ;
    float* lbuf = (float*)(oT + TSZ);        // 2 halves x 8192 rows

    pstats_kernel<<<dim3(512), dim3(256), 0, stream>>>(
        x, partS, partQ, wq, wk, wv, wo, wqb, wkb, wvb, wob, bq, bk, bqk);
    normT_kernel<<<dim3(16, 128, 2), dim3(256), 0, stream>>>(x, partS, partQ, gamma, beta, hT);

    // merged q|k + v GEMM (one launch, 384 blocks x 2 batches)
    gemm_qkv_kernel<<<dim3(384, 1, 2), dim3(256), 0, stream>>>(
        hT, wqb, wvb, qT, vv, bqk, bv);

    // attention: partial jhalf0 -> oT, jhalf1 -> hT (dead), sums -> lbuf
    attn_kernel<<<dim3(256), dim3(512), 0, stream>>>(qT, kT, vv, oT, hT, lbuf);

    // final GEMM with fused combine: out = wo *bt (w0*oT + w1*hT) + bo + x
    gemm_final_kernel<<<dim3(32, 4, 2), dim3(256), 0, stream>>>(
        wob, oT, hT, lbuf, out, bo, x);
}

// Round 19
// 169.381 us; speedup vs baseline: 1.1307x; 1.0083x over previous
//
#include <hip/hip_runtime.h>
#include <stdint.h>

#define NPIX 4096
#define CDIM 512

typedef _Float16 hv8 __attribute__((ext_vector_type(8)));
typedef float f32x4 __attribute__((ext_vector_type(4)));

__device__ __forceinline__ void lds_direct16(const _Float16* g, _Float16* l) {
    __builtin_amdgcn_global_load_lds(
        (const __attribute__((address_space(1))) void*)g,
        (__attribute__((address_space(3))) void*)l, 16, 0, 0);
}

// ---------------- groupnorm partial stats + weight fp32->fp16 conversion ----------------
__global__ void pstats_kernel(const float* __restrict__ x,
                              float* __restrict__ partS, float* __restrict__ partQ,
                              const float* __restrict__ wq, const float* __restrict__ wk,
                              const float* __restrict__ wv, const float* __restrict__ wo,
                              _Float16* __restrict__ d0, _Float16* __restrict__ d1,
                              _Float16* __restrict__ d2, _Float16* __restrict__ d3,
                              const float* __restrict__ bq, const float* __restrict__ bk,
                              float* __restrict__ bqk) {
    int pb = blockIdx.x;                 // 0..511
    int tid = threadIdx.x;

#pragma unroll
    for (int h = 0; h < 2; ++h) {
        int ii = pb * 512 + h * 256 + tid;
        d0[ii] = (_Float16)wq[ii];
        d1[ii] = (_Float16)wk[ii];
        d2[ii] = (_Float16)wv[ii];
        d3[ii] = (_Float16)wo[ii];
        if (ii < 512) bqk[ii] = bq[ii];
        else if (ii < 1024) bqk[ii] = bk[ii - 512];
    }

    int gi = pb >> 3;                    // global group 0..63
    int sl = pb & 7;                     // slice
    const float4* base = (const float4*)x + (long)gi * 16384 + sl * 2048;
    float s = 0.f, sq = 0.f;
    for (int it = 0; it < 8; ++it) {
        float4 f = base[it * 256 + tid];
        s  += f.x + f.y + f.z + f.w;
        sq += f.x * f.x + f.y * f.y + f.z * f.z + f.w * f.w;
    }
    __shared__ float rs[256], rq[256];
    rs[tid] = s; rq[tid] = sq;
    __syncthreads();
    for (int st = 128; st > 0; st >>= 1) {
        if (tid < st) { rs[tid] += rs[tid + st]; rq[tid] += rq[tid + st]; }
        __syncthreads();
    }
    if (tid == 0) { partS[pb] = rs[0]; partQ[pb] = rq[0]; }
}

// ---------------- normalize + transpose (stats finalized inline) ----------------
__global__ void normT_kernel(const float* __restrict__ x,
                             const float* __restrict__ partS, const float* __restrict__ partQ,
                             const float* __restrict__ gamma, const float* __restrict__ beta,
                             _Float16* __restrict__ hT) {
    int b = blockIdx.z, c0 = blockIdx.x * 32, n0 = blockIdx.y * 32;
    int tid = threadIdx.x;
    __shared__ float t[32][33];
    int cl = tid >> 5;
    int nl = tid & 31;
    for (int r = 0; r < 4; ++r)
        t[r * 8 + cl][nl] = x[(long)b * CDIM * NPIX + (long)(c0 + r * 8 + cl) * NPIX + n0 + nl];
    __syncthreads();
    int c = c0 + nl;
    int gg = b * 32 + (c >> 4);
    float s = 0.f, q = 0.f;
#pragma unroll
    for (int k2 = 0; k2 < 8; ++k2) { s += partS[gg * 8 + k2]; q += partQ[gg * 8 + k2]; }
    float m    = s * (1.0f / 65536.0f);
    float rstd = rsqrtf(q * (1.0f / 65536.0f) - m * m + 1e-6f);
    float gm = gamma[c], bt = beta[c];
    for (int r = 0; r < 4; ++r) {
        int nr = r * 8 + cl;
        float val = (t[nl][nr] - m) * rstd * gm + bt;
        hT[(long)b * NPIX * CDIM + (long)(n0 + nr) * CDIM + c] = (_Float16)val;
    }
}

// ---------------- merged q|k + v GEMM, single launch ----------------
__device__ __forceinline__ void gemm_body(
    const _Float16* A, const _Float16* BT, int m0, int n0, int K,
    _Float16* As, _Float16* Bs, f32x4 (&acc)[4][4],
    int tid, int wm, int wn, int lr, int lk) {
    const int nK = K >> 5;
    for (int kt = 0; kt < nK; ++kt) {
        const int kb = kt * 32;
#pragma unroll
        for (int c = 0; c < 2; ++c) {
            int chunk = c * 256 + tid;
            int row = chunk >> 2;
            int k8 = (chunk & 3) * 8;
            _Float16* ldsA = As + (size_t)(c * 256 + (tid & ~63)) * 8;
            _Float16* ldsB = Bs + (size_t)(c * 256 + (tid & ~63)) * 8;
            lds_direct16(A  + (long)(m0 + row) * K + kb + k8, ldsA);
            lds_direct16(BT + (long)(n0 + row) * K + kb + k8, ldsB);
        }
        __syncthreads();
        hv8 af[4], bfr[4];
#pragma unroll
        for (int mi = 0; mi < 4; ++mi)
            af[mi] = *(const hv8*)(As + (size_t)(wm + mi * 16 + lr) * 32 + lk * 8);
#pragma unroll
        for (int ni = 0; ni < 4; ++ni)
            bfr[ni] = *(const hv8*)(Bs + (size_t)(wn + ni * 16 + lr) * 32 + lk * 8);
#pragma unroll
        for (int mi = 0; mi < 4; ++mi)
#pragma unroll
            for (int ni = 0; ni < 4; ++ni)
                acc[mi][ni] = __builtin_amdgcn_mfma_f32_16x16x32_f16(af[mi], bfr[ni], acc[mi][ni], 0, 0, 0);
        __syncthreads();
    }
}

__launch_bounds__(256, 2)
__global__ void gemm_qkv_kernel(const _Float16* __restrict__ hT, const _Float16* __restrict__ wqk,
                                const _Float16* __restrict__ wvb,
                                _Float16* __restrict__ qT, _Float16* __restrict__ vv,
                                const float* __restrict__ bqk, const float* __restrict__ bv) {
    const int b = blockIdx.z;
    const long NC = (long)NPIX * CDIM;
    const int tid = threadIdx.x;
    const int l = tid & 63;
    const int w = tid >> 6;
    const int wm = (w >> 1) * 64;
    const int wn = (w & 1) * 64;
    const int lr = l & 15;
    const int lk = l >> 4;
    __shared__ __align__(16) _Float16 As[128 * 32];
    __shared__ __align__(16) _Float16 Bs[128 * 32];
    f32x4 acc[4][4] = {};

    if (blockIdx.x < 256) {
        const int n0 = (blockIdx.x & 7) * 128;
        const int m0 = (blockIdx.x >> 3) * 128;
        gemm_body(hT + (long)b * NC, wqk, m0, n0, CDIM, As, Bs, acc, tid, wm, wn, lr, lk);
#pragma unroll
        for (int mi = 0; mi < 4; ++mi)
#pragma unroll
            for (int ni = 0; ni < 4; ++ni)
#pragma unroll
                for (int r = 0; r < 4; ++r) {
                    int row = m0 + wm + mi * 16 + lk * 4 + r;
                    int col = n0 + wn + ni * 16 + lr;
                    long qoff = (long)(col >> 9) * (2L * NC);
                    qT[qoff + (long)b * NC + (long)row * CDIM + (col & 511)] =
                        (_Float16)(acc[mi][ni][r] + bqk[col]);
                }
    } else {
        const int xx = blockIdx.x - 256;
        const int n0 = (xx & 31) * 128;
        const int m0 = (xx >> 5) * 128;
        gemm_body(wvb, hT + (long)b * NC, m0, n0, CDIM, As, Bs, acc, tid, wm, wn, lr, lk);
#pragma unroll
        for (int mi = 0; mi < 4; ++mi)
#pragma unroll
            for (int ni = 0; ni < 4; ++ni)
#pragma unroll
                for (int r = 0; r < 4; ++r) {
                    int row = m0 + wm + mi * 16 + lk * 4 + r;
                    int col = n0 + wn + ni * 16 + lr;
                    vv[(long)b * NC + (long)row * NPIX + col] =
                        (_Float16)(acc[mi][ni][r] + bv[row]);
                }
    }
}

// ---------------- final GEMM with fused combine ----------------
__launch_bounds__(256, 2)
__global__ void gemm_final_kernel(const _Float16* __restrict__ A,      // wob [512][512]
                                  const _Float16* __restrict__ p0,
                                  const _Float16* __restrict__ p1,
                                  const float* __restrict__ lbuf,
                                  float* __restrict__ D, const float* __restrict__ bias,
                                  const float* __restrict__ resid) {
    const int b = blockIdx.z;
    const int m0 = blockIdx.y * 128;
    const int n0 = blockIdx.x * 128;
    const int tid = threadIdx.x;
    const int l = tid & 63;
    const int w = tid >> 6;
    const int wm = (w >> 1) * 64;
    const int wn = (w & 1) * 64;
    const int lr = l & 15;
    const int lk = l >> 4;
    __shared__ __align__(16) _Float16 As[128 * 32];
    __shared__ __align__(16) _Float16 Bs[128 * 32];
    __shared__ float wA[128], wB[128];

    if (tid < 128) {
        int rowg = b * NPIX + n0 + tid;
        float l0 = lbuf[rowg], l1 = lbuf[8192 + rowg];
        float inv = 1.0f / (l0 + l1);
        wA[tid] = l0 * inv;
        wB[tid] = l1 * inv;
    }
    __syncthreads();

    const _Float16* pb0 = p0 + (long)b * NPIX * CDIM;
    const _Float16* pb1 = p1 + (long)b * NPIX * CDIM;

    f32x4 acc[4][4] = {};
    for (int kt = 0; kt < 16; ++kt) {
        const int kb = kt * 32;
#pragma unroll
        for (int c = 0; c < 2; ++c) {
            int chunk = c * 256 + tid;
            int row = chunk >> 2;
            int k8 = (chunk & 3) * 8;
            _Float16* ldsA = As + (size_t)(c * 256 + (tid & ~63)) * 8;
            lds_direct16(A + (long)(m0 + row) * CDIM + kb + k8, ldsA);
            long goff = (long)(n0 + row) * CDIM + kb + k8;
            hv8 va = *(const hv8*)(pb0 + goff);
            hv8 vb = *(const hv8*)(pb1 + goff);
            float w0 = wA[row], w1 = wB[row];
            hv8 vo;
#pragma unroll
            for (int i = 0; i < 8; ++i)
                vo[i] = (_Float16)((float)va[i] * w0 + (float)vb[i] * w1);
            *(hv8*)(Bs + (size_t)chunk * 8) = vo;
        }
        __syncthreads();
        hv8 af[4], bfr[4];
#pragma unroll
        for (int mi = 0; mi < 4; ++mi)
            af[mi] = *(const hv8*)(As + (size_t)(wm + mi * 16 + lr) * 32 + lk * 8);
#pragma unroll
        for (int ni = 0; ni < 4; ++ni)
            bfr[ni] = *(const hv8*)(Bs + (size_t)(wn + ni * 16 + lr) * 32 + lk * 8);
#pragma unroll
        for (int mi = 0; mi < 4; ++mi)
#pragma unroll
            for (int ni = 0; ni < 4; ++ni)
                acc[mi][ni] = __builtin_amdgcn_mfma_f32_16x16x32_f16(af[mi], bfr[ni], acc[mi][ni], 0, 0, 0);
        __syncthreads();
    }
#pragma unroll
    for (int mi = 0; mi < 4; ++mi)
#pragma unroll
        for (int ni = 0; ni < 4; ++ni)
#pragma unroll
            for (int r = 0; r < 4; ++r) {
                int row = m0 + wm + mi * 16 + lk * 4 + r;
                int col = n0 + wn + ni * 16 + lr;
                long idx = (long)row * NPIX + col;
                D[(long)b * NPIX * CDIM + idx] =
                    acc[mi][ni][r] + bias[row] + resid[(long)b * NPIX * CDIM + idx];
            }
}

// ---------------- flash attention v19: K/ps TRIPLE-buffered, no per-step drain ----------------
// v11 structure (i-tile 64, j-tile 32, j-split 2, XCD pinning, PV deferred one
// step) with Ks[3]/ps[3]: K(t+2) staged at step t. The implicit pre-PV vmcnt(4)
// (for vf, issued one full step earlier) also drains stage(t+1); ENDBAR's
// vmcnt(8) is a steady-state no-op (8 ops in flight: stage(t+2)+vload(t)).
// Only lgkmcnt(0)+barrier remain on the per-step critical path.
__launch_bounds__(512, 2)
__global__ void attn_kernel(const _Float16* __restrict__ qT, const _Float16* __restrict__ kT,
                            const _Float16* __restrict__ v,
                            _Float16* __restrict__ p0, _Float16* __restrict__ p1,
                            float* __restrict__ lbuf) {
    __shared__ __align__(16) _Float16 Ks[3][32 * 512];   // 96 KB, rows 1 KB, XOR (j&7)<<4
    __shared__ __align__(16) char ps[3][64 * 80];        // 15 KB, 80 B rows
    __shared__ float red[8][64];
    __shared__ float redt[64];

    const int g = blockIdx.x;
    const int xcd = g & 7;
    const int comb = xcd >> 1;                       // (batch, jhalf)
    const int itile = ((g >> 3) << 1) | (xcd & 1);   // 0..63
    const int batch = comb >> 1;
    const int jhalf = comb & 1;
    const int i0 = itile * 64;
    const int jbase = jhalf * 2048;

    const int tid = threadIdx.x;
    const int l = tid & 63, w = tid >> 6;
    const int lr = l & 15, lk = l >> 4;
    const int iq = w >> 1, jq = w & 1;               // QK: rows iq*16, cols jq*16

    const _Float16* qb = qT + (long)batch * NPIX * CDIM;
    const _Float16* kb = kT + (long)batch * NPIX * CDIM;
    const _Float16* vb = v  + (long)batch * CDIM * NPIX;

    hv8 af[16];
    {
        const _Float16* qr = qb + (long)(i0 + iq * 16 + lr) * CDIM + lk * 8;
#pragma unroll
        for (int kk = 0; kk < 16; ++kk)
            af[kk] = *(const hv8*)(qr + kk * 32);
    }

    f32x4 oacc[4][4] = {};
    float lsum[4] = {};
    hv8 vf[4];

    const _Float16* vptr = vb + (long)(w * 64 + lr) * NPIX + jbase + lk * 8;
    const float scale = 0.044194173824159216f;   // 1/sqrt(512)

#define STAGE(BUF, JT)                                                               \
    {                                                                                \
        const long j0s = (long)jbase + (JT) * 32;                                    \
        _Float16* kd = Ks[BUF];                                                      \
        _Pragma("unroll")                                                            \
        for (int q = 0; q < 4; ++q) {                                                \
            int row = q * 8 + w;                                                     \
            int cc = l ^ (row & 7);                                                  \
            lds_direct16(kb + (j0s + row) * CDIM + cc * 8, kd + row * 512);          \
        }                                                                            \
    }

#define VLOAD(JT)                                                                    \
    {                                                                                \
        _Pragma("unroll")                                                            \
        for (int ni = 0; ni < 4; ++ni)                                               \
            vf[ni] = *(const hv8*)(vptr + (long)ni * (16 * NPIX) + (JT) * 32);       \
    }

#define QKEXP(CUR)                                                                   \
    {                                                                                \
        const char* kbase = (const char*)Ks[CUR];                                    \
        f32x4 sa = {}, sb = {};                                                      \
        const int jj = jq * 16 + lr;                                                 \
        const uint32_t sw = (uint32_t)((jj & 7) << 4);                               \
        _Pragma("unroll")                                                            \
        for (int kk = 0; kk < 8; ++kk) {                                             \
            hv8 b0 = *(const hv8*)(kbase + (((uint32_t)(jj * 1024 + (2 * kk) * 64 + lk * 16)) ^ sw));     \
            sa = __builtin_amdgcn_mfma_f32_16x16x32_f16(af[2 * kk], b0, sa, 0, 0, 0);                     \
            hv8 b1 = *(const hv8*)(kbase + (((uint32_t)(jj * 1024 + (2 * kk + 1) * 64 + lk * 16)) ^ sw)); \
            sb = __builtin_amdgcn_mfma_f32_16x16x32_f16(af[2 * kk + 1], b1, sb, 0, 0, 0);                 \
        }                                                                            \
        sa += sb;                                                                    \
        _Pragma("unroll")                                                            \
        for (int r = 0; r < 4; ++r) {                                                \
            float p = __expf(sa[r] * scale);                                         \
            lsum[r] += p;                                                            \
            int i = iq * 16 + lk * 4 + r;                                            \
            int j2 = jq * 16 + lr;                                                   \
            *(_Float16*)(ps[CUR] + i * 80 + j2 * 2) = (_Float16)p;                   \
        }                                                                            \
    }

#define PVSTEP(PRV)                                                                  \
    {                                                                                \
        _Pragma("unroll")                                                            \
        for (int mi = 0; mi < 4; ++mi) {                                             \
            int i2 = mi * 16 + lr;                                                   \
            hv8 pa = *(const hv8*)(ps[PRV] + i2 * 80 + lk * 16);                     \
            _Pragma("unroll")                                                        \
            for (int ni = 0; ni < 4; ++ni)                                           \
                oacc[mi][ni] = __builtin_amdgcn_mfma_f32_16x16x32_f16(pa, vf[ni], oacc[mi][ni], 0, 0, 0); \
        }                                                                            \
    }

#define ENDBAR(N)                                                                    \
    __builtin_amdgcn_sched_barrier(0);                                               \
    asm volatile("s_waitcnt vmcnt(" #N ") lgkmcnt(0)" ::: "memory");                 \
    __builtin_amdgcn_s_barrier();                                                    \
    __builtin_amdgcn_sched_barrier(0);

// C = JT % 3 (literal). PV reads ps[(JT-1)%3] = ps[(C+2)%3].
#define STEP(JT, C)                                                                  \
    {                                                                                \
        if ((JT) < 62) STAGE((((C) + 2) % 3), (JT) + 2)                              \
        __builtin_amdgcn_sched_barrier(0);                                           \
        __builtin_amdgcn_s_setprio(1);                                               \
        QKEXP(C)                                                                     \
        PVSTEP((((C) + 2) % 3))                                                      \
        __builtin_amdgcn_s_setprio(0);                                               \
        __builtin_amdgcn_sched_barrier(0);                                           \
        VLOAD(JT)                                                                    \
        ENDBAR(8)                                                                    \
    }

    // prologue: stage K(0), K(1); drain K(0) only (K(1) stays in flight)
    STAGE(0, 0)
    STAGE(1, 1)
    __builtin_amdgcn_sched_barrier(0);
    asm volatile("s_waitcnt vmcnt(4)" ::: "memory");
    __builtin_amdgcn_s_barrier();
    __builtin_amdgcn_sched_barrier(0);

    // step 0: no PV yet; ENDBAR(8) drains stage(1) (12 in flight -> keep 8)
    STAGE(2, 2)
    __builtin_amdgcn_sched_barrier(0);
    __builtin_amdgcn_s_setprio(1);
    QKEXP(0)
    __builtin_amdgcn_s_setprio(0);
    __builtin_amdgcn_sched_barrier(0);
    VLOAD(0)
    ENDBAR(8)

    // steady: steps 1..63 in trios (stride-3 keeps mod-3 phase literal)
    for (int jt = 1; jt < 64; jt += 3) {
        STEP(jt,     1)
        STEP(jt + 1, 2)
        STEP(jt + 2, 0)
    }

    // epilogue: PV(63) reads ps[63%3=0]; drain the last V loads first
    asm volatile("s_waitcnt vmcnt(0)" ::: "memory");
    __builtin_amdgcn_sched_barrier(0);
    PVSTEP(0)

#pragma unroll
    for (int m = 1; m <= 8; m <<= 1)
#pragma unroll
        for (int r = 0; r < 4; ++r)
            lsum[r] += __shfl_xor(lsum[r], m, 64);
    if (lr == 0)
#pragma unroll
        for (int r = 0; r < 4; ++r)
            red[w][iq * 16 + lk * 4 + r] = lsum[r];
    __syncthreads();
    if (tid < 64) {
        int iq2 = tid >> 4;
        float lv = red[iq2 * 2][tid] + red[iq2 * 2 + 1][tid];
        redt[tid] = 1.0f / lv;
        lbuf[jhalf * 8192 + batch * NPIX + i0 + tid] = lv;
    }
    __syncthreads();

    _Float16* dsth = (jhalf ? p1 : p0) + (long)batch * NPIX * CDIM;
#pragma unroll
    for (int mi = 0; mi < 4; ++mi)
#pragma unroll
        for (int r = 0; r < 4; ++r) {
            int row = mi * 16 + lk * 4 + r;
            float rv = redt[row];
#pragma unroll
            for (int ni = 0; ni < 4; ++ni) {
                int c = w * 64 + ni * 16 + lr;
                dsth[(long)(i0 + row) * CDIM + c] = (_Float16)(oacc[mi][ni][r] * rv);
            }
        }
#undef STEP
#undef ENDBAR
#undef PVSTEP
#undef QKEXP
#undef VLOAD
#undef STAGE
}

extern "C" void kernel_launch(void* const* d_in, const int* in_sizes, int n_in,
                              void* d_out, int out_size, void* d_ws, size_t ws_size,
                              hipStream_t stream) {
    const float* x     = (const float*)d_in[0];
    const float* gamma = (const float*)d_in[1];
    const float* beta  = (const float*)d_in[2];
    const float* wq    = (const float*)d_in[3];
    const float* bq    = (const float*)d_in[4];
    const float* wk    = (const float*)d_in[5];
    const float* bk    = (const float*)d_in[6];
    const float* wv    = (const float*)d_in[7];
    const float* bv    = (const float*)d_in[8];
    const float* wo    = (const float*)d_in[9];
    const float* bo    = (const float*)d_in[10];
    float* out = (float*)d_out;

    char* ws = (char*)d_ws;
    float* partS = (float*)ws;               // 512
    float* partQ = partS + 512;              // 512
    float* bqk   = partQ + 512;              // 1024
    _Float16* wqb = (_Float16*)(ws + 8192);  // wq|wk adjacent -> fused BT [1024][512]
    _Float16* wkb = wqb + 262144;
    _Float16* wvb = wkb + 262144;
    _Float16* wob = wvb + 262144;
    _Float16* hT  = wob + 262144;
    const long TSZ = (long)2 * NPIX * CDIM;
    _Float16* qT = hT + TSZ;
    _Float16* kT = qT + TSZ;                 // = qT + 2*NPIX*CDIM (split-store relies on this)
    _Float16* vv = kT + TSZ;
    _Float16* oT = vv + TSZ;
    float* lbuf = (float*)(oT + TSZ);        // 2 halves x 8192 rows

    pstats_kernel<<<dim3(512), dim3(256), 0, stream>>>(
        x, partS, partQ, wq, wk, wv, wo, wqb, wkb, wvb, wob, bq, bk, bqk);
    normT_kernel<<<dim3(16, 128, 2), dim3(256), 0, stream>>>(x, partS, partQ, gamma, beta, hT);

    gemm_qkv_kernel<<<dim3(384, 1, 2), dim3(256), 0, stream>>>(
        hT, wqb, wvb, qT, vv, bqk, bv);

    attn_kernel<<<dim3(256), dim3(512), 0, stream>>>(qT, kT, vv, oT, hT, lbuf);

    gemm_final_kernel<<<dim3(32, 4, 2), dim3(256), 0, stream>>>(
        wob, oT, hT, lbuf, out, bo, x);
}